// Round 9
// baseline (294.637 us; speedup 1.0000x reference)
//
#include <hip/hip_runtime.h>
#include <cstdint>
#include <cstddef>

#define NC    4096   // row length
#define NTHR  256

// split config: 1 row per wave
#define RBLK   2048                    // row-kernel grid (x 4 waves = 8192 rows)
#define WPB    4                       // waves per block
#define ROWS   (RBLK * WPB)            // 8192
#define ABLK   1024                    // absmax grid (16 waves/CU for HBM sat)

typedef float v4f __attribute__((ext_vector_type(4)));

static __device__ __forceinline__ float waveReduceMax(float v) {
    #pragma unroll
    for (int off = 32; off > 0; off >>= 1)
        v = fmaxf(v, __shfl_down(v, off, 64));
    return v;
}

// leading syncthreads removes WAR race on s4 between consecutive reduces
__device__ __forceinline__ float blockMax(float v, float* s4, int tid) {
    v = waveReduceMax(v);
    int lane = tid & 63, wid = tid >> 6;
    __syncthreads();
    if (lane == 0) s4[wid] = v;
    __syncthreads();
    return fmaxf(fmaxf(s4[0], s4[1]), fmaxf(s4[2], s4[3]));
}

// LUT-free: lut[msb]/65536 == rintf(exp2f(16 - msb/2))/65536 exactly for all
// 16 entries. No runtime-indexed array -> no scratch (round-5 proven).
__device__ __forceinline__ void rowStatCompute(float Ex, float Ex2,
                                               float* mu_o, float* inv_o) {
    float mu  = Ex * (1.f / NC);
    float var = __fsub_rn(Ex2 * (1.f / NC), __fmul_rn(mu, mu));
    float var_f = fminf(fmaxf(rintf(var), 1.f), 65535.f);
    int vi = (int)var_f;
    int msb = min(31 - __clz(vi), 15);
    float lutv = rintf(exp2f(16.f - 0.5f * (float)msb));
    *mu_o  = mu;
    *inv_o = lutv * (1.f / 65536.f);
}

// ---- k1: global absmax partials, plain stores (no atomics -> no init) ----
__global__ __launch_bounds__(NTHR) void k_absmax_s(const float* __restrict__ x,
                                                   float* __restrict__ blockmax,
                                                   int n4) {
    const float4* x4 = (const float4*)x;
    int t = blockIdx.x * NTHR + threadIdx.x;
    int S = gridDim.x * NTHR;
    float m = 0.f;
    int full = (n4 / (S * 8)) * (S * 8);
    for (int base = t; base < full; base += S * 8) {
        float4 v[8];
        #pragma unroll
        for (int u = 0; u < 8; ++u) v[u] = x4[base + u * S];
        #pragma unroll
        for (int u = 0; u < 8; ++u)
            m = fmaxf(m, fmaxf(fmaxf(fabsf(v[u].x), fabsf(v[u].y)),
                               fmaxf(fabsf(v[u].z), fabsf(v[u].w))));
    }
    for (int i = full + t; i < n4; i += S) {
        float4 v = x4[i];
        m = fmaxf(m, fmaxf(fmaxf(fabsf(v.x), fabsf(v.y)),
                           fmaxf(fabsf(v.z), fabsf(v.w))));
    }
    __shared__ float s4[4];
    float b = blockMax(m, s4, threadIdx.x);
    if (threadIdx.x == 0) blockmax[blockIdx.x] = b;
}

// per-float4 quantize+stats, packed int8 -> LDS
#define QPROC(V, EIDX)                                                        \
    {                                                                         \
        const float* pv = (const float*)&(V);                                 \
        int p = 0;                                                            \
        _Pragma("unroll")                                                     \
        for (int j = 0; j < 4; ++j) {                                         \
            float xi = fminf(fmaxf(rintf(pv[j] * r_in), -127.f), 127.f);      \
            int ii = (int)xi;                                                 \
            p |= (ii & 255) << (8 * j);                                       \
            float q = xi * scale_in;                                          \
            ex += q;                                                          \
            float aq = fabsf(q);                                              \
            bool hi = aq >= 64.f;                                             \
            int idx = hi ? min((int)(aq * 0.0625f), 15)                       \
                         : (((int)(aq * 0.5f)) & 15);                         \
            float sq = (float)(idx * idx);                                    \
            ex2 += hi ? sq * 256.f : sq * 16.f;                               \
        }                                                                     \
        lds_pk[wloc][lane + 64 * (EIDX)] = p;                                 \
    }

// per-float4 |y| contribution from LDS-packed int8
#define YPROC(G, B, P)                                                        \
    {                                                                         \
        const float* pg = (const float*)&(G);                                 \
        const float* pb = (const float*)&(B);                                 \
        _Pragma("unroll")                                                     \
        for (int j = 0; j < 4; ++j) {                                         \
            int ii = ((P) << (24 - 8 * j)) >> 24;                             \
            float q = (float)ii * scale_in;                                   \
            float y = (q - mu) * inv * pg[j] + pb[j];                         \
            ym = fmaxf(ym, fabsf(y));                                         \
        }                                                                     \
    }

// per-float4 finalize: requantize from x, scale, NT store
#define OPROC(XV, G, B, EIDX)                                                 \
    {                                                                         \
        const float* px = (const float*)&(XV);                                \
        const float* pg = (const float*)&(G);                                 \
        const float* pb = (const float*)&(B);                                 \
        v4f o;                                                                \
        _Pragma("unroll")                                                     \
        for (int j = 0; j < 4; ++j) {                                         \
            float xi = fminf(fmaxf(rintf(px[j] * r_in), -127.f), 127.f);      \
            float q = xi * scale_in;                                          \
            float y = (q - mu) * inv * pg[j] + pb[j];                         \
            float yi = fminf(fmaxf(rintf(y * r_out), -127.f), 127.f);         \
            o[j] = yi * scale_out;                                            \
        }                                                                     \
        __builtin_nontemporal_store(o, (v4f*)(outr + (lane + 64 * (EIDX)) * 4)); \
    }

// ---- k2: per-row stats + |y|max. 1 row/wave; single x read; pk in LDS.
// First x batch is issued BEFORE the scale_in block-reduce: __syncthreads is a
// codegen barrier, so without the manual hoist those L3 loads (~300-500cy)
// serialize behind the reduce. No occupancy attributes (backfired 3/3).
__global__ __launch_bounds__(NTHR) void k_rowstats_s(
    const float* __restrict__ x,
    const float* __restrict__ gamma,
    const float* __restrict__ beta,
    const float* __restrict__ blockmax,   // [ABLK] from k1
    float2* __restrict__ row_stats,       // [ROWS] plain stores
    float* __restrict__ bmax2)            // [RBLK] plain stores
{
    const int tid  = threadIdx.x;
    const int lane = tid & 63;
    const int wloc = tid >> 6;
    const int row  = blockIdx.x * WPB + wloc;
    __shared__ float s4[4];
    __shared__ int lds_pk[WPB][NC / 4];   // 16 KB packed int8

    const float4* xr = (const float4*)(x + (size_t)row * NC);
    const float4* g4 = (const float4*)gamma;
    const float4* b4 = (const float4*)beta;

    // hoisted batch 0 (independent of scale_in) — overlaps the reduce below
    float4 v0 = xr[lane + 64 * 0];
    float4 v1 = xr[lane + 64 * 1];
    float4 v2 = xr[lane + 64 * 2];
    float4 v3 = xr[lane + 64 * 3];
    float4 v4 = xr[lane + 64 * 4];
    float4 v5 = xr[lane + 64 * 5];
    float4 v6 = xr[lane + 64 * 6];
    float4 v7 = xr[lane + 64 * 7];

    // scale_in: identical deterministic reduce in every block
    float pm = 0.f;
    #pragma unroll
    for (int i = 0; i < ABLK / NTHR; ++i)
        pm = fmaxf(pm, blockmax[tid + NTHR * i]);
    const float gmax = blockMax(pm, s4, tid);
    const float scale_in = gmax * (1.0f / 127.0f);
    const float r_in = 1.0f / scale_in;

    // pass 1: quantize row -> LDS pk, accumulate Ex/Ex2
    float ex = 0.f, ex2 = 0.f;
    QPROC(v0, 0) QPROC(v1, 1) QPROC(v2, 2) QPROC(v3, 3)
    QPROC(v4, 4) QPROC(v5, 5) QPROC(v6, 6) QPROC(v7, 7)
    {
        float4 w0 = xr[lane + 64 * 8];
        float4 w1 = xr[lane + 64 * 9];
        float4 w2 = xr[lane + 64 * 10];
        float4 w3 = xr[lane + 64 * 11];
        float4 w4 = xr[lane + 64 * 12];
        float4 w5 = xr[lane + 64 * 13];
        float4 w6 = xr[lane + 64 * 14];
        float4 w7 = xr[lane + 64 * 15];
        QPROC(w0, 8)  QPROC(w1, 9)  QPROC(w2, 10) QPROC(w3, 11)
        QPROC(w4, 12) QPROC(w5, 13) QPROC(w6, 14) QPROC(w7, 15)
    }
    // xor-butterfly: fp-add commutativity -> bit-identical in every lane,
    // no broadcast needed
    #pragma unroll
    for (int off = 1; off < 64; off <<= 1) {
        ex  += __shfl_xor(ex,  off, 64);
        ex2 += __shfl_xor(ex2, off, 64);
    }
    float mu, inv;
    rowStatCompute(ex, ex2, &mu, &inv);
    if (lane == 0) row_stats[row] = make_float2(mu, inv);

    // pass 2: row |y| max from LDS pk (same-wave LDS: no barrier needed)
    float ym = 0.f;
    #pragma unroll 1
    for (int e = 0; e < 16; e += 2) {
        float4 gA = g4[lane + 64 * e];
        float4 gB = g4[lane + 64 * (e + 1)];
        float4 bA = b4[lane + 64 * e];
        float4 bB = b4[lane + 64 * (e + 1)];
        int pA = lds_pk[wloc][lane + 64 * e];
        int pB = lds_pk[wloc][lane + 64 * (e + 1)];
        YPROC(gA, bA, pA)
        YPROC(gB, bB, pB)
    }
    #pragma unroll
    for (int off = 1; off < 64; off <<= 1)
        ym = fmaxf(ym, __shfl_xor(ym, off, 64));
    float bym = blockMax(ym, s4, tid);
    if (tid == 0) bmax2[blockIdx.x] = bym;
}

// ---- k3: scale_out reduce + finalize. Requantizes from x (L3-hot); first
// iteration's loads + row_stats hoisted above both block-reduces.
__global__ __launch_bounds__(NTHR) void k_finalize_s(
    const float* __restrict__ x,
    const float* __restrict__ gamma,
    const float* __restrict__ beta,
    const float* __restrict__ blockmax,   // [ABLK]
    const float* __restrict__ bmax2,      // [RBLK]
    const float2* __restrict__ row_stats, // [ROWS]
    float* __restrict__ out)
{
    const int tid  = threadIdx.x;
    const int lane = tid & 63;
    const int wloc = tid >> 6;
    const int row  = blockIdx.x * WPB + wloc;
    __shared__ float s4[4];

    const float4* xr = (const float4*)(x + (size_t)row * NC);
    const float4* g4 = (const float4*)gamma;
    const float4* b4 = (const float4*)beta;
    float* outr = out + (size_t)row * NC;

    // hoisted loads (independent of both reduces)
    const float2 st = row_stats[row];
    float4 x0 = xr[lane + 64 * 0];
    float4 x1 = xr[lane + 64 * 1];
    float4 g0 = g4[lane + 64 * 0];
    float4 g1 = g4[lane + 64 * 1];
    float4 b0 = b4[lane + 64 * 0];
    float4 b1 = b4[lane + 64 * 1];

    // scale_in (identical reduce as k2 -> bit-identical)
    float pm = 0.f;
    #pragma unroll
    for (int i = 0; i < ABLK / NTHR; ++i)
        pm = fmaxf(pm, blockmax[tid + NTHR * i]);
    const float gmax = blockMax(pm, s4, tid);
    const float scale_in = gmax * (1.0f / 127.0f);
    const float r_in = 1.0f / scale_in;

    // scale_out: identical deterministic reduce in every block (8/thread)
    float pm2 = 0.f;
    #pragma unroll
    for (int i = 0; i < RBLK / NTHR; ++i)
        pm2 = fmaxf(pm2, bmax2[tid + NTHR * i]);
    const float ygmax = blockMax(pm2, s4, tid);
    const float scale_out = ygmax * (1.f / 127.f);
    const float r_out = 1.f / scale_out;

    const float mu = st.x, inv = st.y;

    OPROC(x0, g0, b0, 0)
    OPROC(x1, g1, b1, 1)
    #pragma unroll 1
    for (int e = 2; e < 16; e += 2) {
        float4 xA = xr[lane + 64 * e];
        float4 xB = xr[lane + 64 * (e + 1)];
        float4 gA = g4[lane + 64 * e];
        float4 gB = g4[lane + 64 * (e + 1)];
        float4 bA = b4[lane + 64 * e];
        float4 bB = b4[lane + 64 * (e + 1)];
        OPROC(xA, gA, bA, e)
        OPROC(xB, gB, bB, e + 1)
    }
}

// ---------------- fallback path (round-2 proven, one row/block) ----------------
__global__ __launch_bounds__(NTHR) void k_absmax(const float* __restrict__ x,
                                                 unsigned int* __restrict__ amax_bits,
                                                 int n4) {
    const float4* x4 = (const float4*)x;
    int t = blockIdx.x * NTHR + threadIdx.x;
    int S = gridDim.x * NTHR;
    float m = 0.f;
    int full = (n4 / (S * 8)) * (S * 8);
    for (int base = t; base < full; base += S * 8) {
        float4 v[8];
        #pragma unroll
        for (int u = 0; u < 8; ++u) v[u] = x4[base + u * S];
        #pragma unroll
        for (int u = 0; u < 8; ++u)
            m = fmaxf(m, fmaxf(fmaxf(fabsf(v[u].x), fabsf(v[u].y)),
                               fmaxf(fabsf(v[u].z), fabsf(v[u].w))));
    }
    for (int i = full + t; i < n4; i += S) {
        float4 v = x4[i];
        m = fmaxf(m, fmaxf(fmaxf(fabsf(v.x), fabsf(v.y)),
                           fmaxf(fabsf(v.z), fabsf(v.w))));
    }
    __shared__ float s4[4];
    float b = blockMax(m, s4, threadIdx.x);
    if (threadIdx.x == 0) atomicMax(amax_bits, __float_as_uint(b));
}

__global__ __launch_bounds__(256) void k_rowstats_fb(
    const float* __restrict__ x, const float* __restrict__ gamma,
    const float* __restrict__ beta, const unsigned int* __restrict__ amax_x_bits,
    unsigned int* __restrict__ amax_y_bits, float2* __restrict__ row_stats,
    int* __restrict__ xi8)
{
    const int row = blockIdx.x;
    const float scale_in = __uint_as_float(*amax_x_bits) * (1.0f / 127.0f);
    const float r_in = 1.0f / scale_in;
    const float4* xr = (const float4*)(x + (size_t)row * NC);
    const float4* g4 = (const float4*)gamma;
    const float4* b4 = (const float4*)beta;
    int pack[4];
    float ex = 0.f, ex2 = 0.f;
    #pragma unroll
    for (int k = 0; k < 4; ++k) {
        float4 v = xr[threadIdx.x + k * 256];
        const float* pv = (const float*)&v;
        int pk = 0;
        #pragma unroll
        for (int j = 0; j < 4; ++j) {
            float xi = fminf(fmaxf(rintf(pv[j] * r_in), -127.f), 127.f);
            int ii = (int)xi;
            pk |= (ii & 255) << (8 * j);
            float q = xi * scale_in;
            ex += q;
            float aq = fabsf(q);
            bool hi = aq >= 64.f;
            int idx = hi ? min((int)(aq * 0.0625f), 15) : (((int)(aq * 0.5f)) & 15);
            float sq = (float)(idx * idx);
            ex2 += hi ? sq * 256.f : sq * 16.f;
        }
        pack[k] = pk;
    }
    int* wr = xi8 + (size_t)row * (NC / 4);
    #pragma unroll
    for (int k = 0; k < 4; ++k) wr[threadIdx.x + k * 256] = pack[k];
    #pragma unroll
    for (int off = 1; off < 64; off <<= 1) {
        ex  += __shfl_xor(ex,  off, 64);
        ex2 += __shfl_xor(ex2, off, 64);
    }
    __shared__ float sred[8];
    __shared__ float sbc[2];
    int lane = threadIdx.x & 63, wid = threadIdx.x >> 6;
    if (lane == 0) { sred[wid] = ex; sred[4 + wid] = ex2; }
    __syncthreads();
    if (threadIdx.x == 0) {
        float Ex  = (sred[0] + sred[1]) + (sred[2] + sred[3]);
        float Ex2 = (sred[4] + sred[5]) + (sred[6] + sred[7]);
        float mu, inv;
        rowStatCompute(Ex, Ex2, &mu, &inv);
        sbc[0] = mu; sbc[1] = inv;
        row_stats[row] = make_float2(mu, inv);
    }
    __syncthreads();
    const float mu = sbc[0], inv = sbc[1];
    float ym = 0.f;
    #pragma unroll
    for (int k = 0; k < 4; ++k) {
        float4 g = g4[threadIdx.x + k * 256];
        float4 b = b4[threadIdx.x + k * 256];
        const float* pg = (const float*)&g;
        const float* pb = (const float*)&b;
        int pk = pack[k];
        #pragma unroll
        for (int j = 0; j < 4; ++j) {
            int ii = (pk << (24 - 8 * j)) >> 24;
            float q = (float)ii * scale_in;
            float y = (q - mu) * inv * pg[j] + pb[j];
            ym = fmaxf(ym, fabsf(y));
        }
    }
    __syncthreads();
    __shared__ float smax[4];
    float b = blockMax(ym, smax, threadIdx.x);
    if (threadIdx.x == 0) atomicMax(amax_y_bits, __float_as_uint(b));
}

__global__ __launch_bounds__(256) void k_finalize_fb(
    const int* __restrict__ xi8, const float* __restrict__ gamma,
    const float* __restrict__ beta, const unsigned int* __restrict__ amax_x_bits,
    const unsigned int* __restrict__ amax_y_bits,
    const float2* __restrict__ row_stats, float* __restrict__ out)
{
    const int row = blockIdx.x;
    const float scale_in  = __uint_as_float(*amax_x_bits) * (1.0f / 127.0f);
    const float scale_out = __uint_as_float(*amax_y_bits) * (1.0f / 127.0f);
    const float r_out = 1.0f / scale_out;
    const float2 st = row_stats[row];
    const float mu = st.x, inv = st.y;
    const int* xr = xi8 + (size_t)row * (NC / 4);
    float4* outr = (float4*)(out + (size_t)row * NC);
    const float4* g4 = (const float4*)gamma;
    const float4* b4 = (const float4*)beta;
    #pragma unroll
    for (int k = 0; k < 4; ++k) {
        int pk = xr[threadIdx.x + k * 256];
        float4 g = g4[threadIdx.x + k * 256];
        float4 b = b4[threadIdx.x + k * 256];
        float4 o;
        const float* pg = (const float*)&g;
        const float* pb = (const float*)&b;
        float* po = (float*)&o;
        #pragma unroll
        for (int j = 0; j < 4; ++j) {
            int ii = (pk << (24 - 8 * j)) >> 24;
            float q = (float)ii * scale_in;
            float y = (q - mu) * inv * pg[j] + pb[j];
            float yi = fminf(fmaxf(rintf(y * r_out), -127.f), 127.f);
            po[j] = yi * scale_out;
        }
        outr[threadIdx.x + k * 256] = o;
    }
}

extern "C" void kernel_launch(void* const* d_in, const int* in_sizes, int n_in,
                              void* d_out, int out_size, void* d_ws, size_t ws_size,
                              hipStream_t stream) {
    const float* x     = (const float*)d_in[0];
    const float* gamma = (const float*)d_in[1];
    const float* beta  = (const float*)d_in[2];
    float* out = (float*)d_out;

    const int n    = in_sizes[0];
    const int rows = n / NC;
    const int n4   = n / 4;

    // split ws layout (all plain-store, no init needed):
    //   blockmax[ABLK] @0, bmax2[RBLK] after, row_stats[ROWS] after
    const size_t ws_need = 4 * (size_t)ABLK + 4 * (size_t)RBLK + 8 * (size_t)ROWS;

    if (rows == ROWS && n == ROWS * NC && ws_size >= ws_need) {
        float* blockmax   = (float*)d_ws;
        float* bmax2      = (float*)((char*)d_ws + 4 * (size_t)ABLK);
        float2* row_stats = (float2*)((char*)d_ws + 4 * (size_t)ABLK
                                                  + 4 * (size_t)RBLK);
        k_absmax_s<<<ABLK, NTHR, 0, stream>>>(x, blockmax, n4);
        k_rowstats_s<<<RBLK, NTHR, 0, stream>>>(x, gamma, beta, blockmax,
                                                row_stats, bmax2);
        k_finalize_s<<<RBLK, NTHR, 0, stream>>>(x, gamma, beta, blockmax,
                                                bmax2, row_stats, out);
    } else {
        // proven fallback: absmax -> rowstats -> finalize (atomic path)
        unsigned int* amax_x = (unsigned int*)d_ws;
        unsigned int* amax_y = (unsigned int*)((char*)d_ws + 8);
        float2* row_stats    = (float2*)((char*)d_ws + 4096);
        size_t i8_off = (4096 + (size_t)rows * 8 + 255) & ~(size_t)255;
        int* xi8 = (int*)((char*)d_ws + i8_off);

        (void)hipMemsetAsync(d_ws, 0, 4096, stream);
        k_absmax<<<512, NTHR, 0, stream>>>(x, amax_x, n4);
        k_rowstats_fb<<<rows, NTHR, 0, stream>>>(x, gamma, beta, amax_x, amax_y,
                                                 row_stats, xi8);
        k_finalize_fb<<<rows, NTHR, 0, stream>>>(xi8, gamma, beta, amax_x, amax_y,
                                                 row_stats, out);
    }
}

// Round 10
// 280.974 us; speedup vs baseline: 1.0486x; 1.0486x over previous
//
#include <hip/hip_runtime.h>
#include <cstdint>
#include <cstddef>

#define NC    4096   // row length
#define NTHR  256

// split config: 1 row per wave
#define RBLK   2048                    // row-kernel grid (x 4 waves = 8192 rows)
#define WPB    4                       // waves per block
#define ROWS   (RBLK * WPB)            // 8192
#define ABLK   512                     // absmax grid

typedef float v4f __attribute__((ext_vector_type(4)));

static __device__ __forceinline__ float waveReduceMax(float v) {
    #pragma unroll
    for (int off = 32; off > 0; off >>= 1)
        v = fmaxf(v, __shfl_down(v, off, 64));
    return v;
}

// leading syncthreads removes WAR race on s4 between consecutive reduces
__device__ __forceinline__ float blockMax(float v, float* s4, int tid) {
    v = waveReduceMax(v);
    int lane = tid & 63, wid = tid >> 6;
    __syncthreads();
    if (lane == 0) s4[wid] = v;
    __syncthreads();
    return fmaxf(fmaxf(s4[0], s4[1]), fmaxf(s4[2], s4[3]));
}

// LUT-free: lut[msb]/65536 == rintf(exp2f(16 - msb/2))/65536 exactly for all
// 16 entries (odd entries 46341,23170,11585,5793,2896,1448,724,362 verified).
// No runtime-indexed array -> no scratch (round-5 proven).
__device__ __forceinline__ void rowStatCompute(float Ex, float Ex2,
                                               float* mu_o, float* inv_o) {
    float mu  = Ex * (1.f / NC);
    float var = __fsub_rn(Ex2 * (1.f / NC), __fmul_rn(mu, mu));
    float var_f = fminf(fmaxf(rintf(var), 1.f), 65535.f);
    int vi = (int)var_f;
    int msb = min(31 - __clz(vi), 15);
    float lutv = rintf(exp2f(16.f - 0.5f * (float)msb));
    *mu_o  = mu;
    *inv_o = lutv * (1.f / 65536.f);
}

// ---- k1: global absmax partials, plain stores (no atomics -> no init) ----
__global__ __launch_bounds__(NTHR) void k_absmax_s(const float* __restrict__ x,
                                                   float* __restrict__ blockmax,
                                                   int n4) {
    const float4* x4 = (const float4*)x;
    int t = blockIdx.x * NTHR + threadIdx.x;
    int S = gridDim.x * NTHR;
    float m = 0.f;
    int full = (n4 / (S * 8)) * (S * 8);
    for (int base = t; base < full; base += S * 8) {
        float4 v[8];
        #pragma unroll
        for (int u = 0; u < 8; ++u) v[u] = x4[base + u * S];
        #pragma unroll
        for (int u = 0; u < 8; ++u)
            m = fmaxf(m, fmaxf(fmaxf(fabsf(v[u].x), fabsf(v[u].y)),
                               fmaxf(fabsf(v[u].z), fabsf(v[u].w))));
    }
    for (int i = full + t; i < n4; i += S) {
        float4 v = x4[i];
        m = fmaxf(m, fmaxf(fmaxf(fabsf(v.x), fabsf(v.y)),
                           fmaxf(fabsf(v.z), fabsf(v.w))));
    }
    __shared__ float s4[4];
    float b = blockMax(m, s4, threadIdx.x);
    if (threadIdx.x == 0) blockmax[blockIdx.x] = b;
}

// per-float4 quantize+stats, packed int8 -> LDS
#define QPROC(V, EIDX)                                                        \
    {                                                                         \
        const float* pv = (const float*)&(V);                                 \
        int p = 0;                                                            \
        _Pragma("unroll")                                                     \
        for (int j = 0; j < 4; ++j) {                                         \
            float xi = fminf(fmaxf(rintf(pv[j] * r_in), -127.f), 127.f);      \
            int ii = (int)xi;                                                 \
            p |= (ii & 255) << (8 * j);                                       \
            float q = xi * scale_in;                                          \
            ex += q;                                                          \
            float aq = fabsf(q);                                              \
            bool hi = aq >= 64.f;                                             \
            int idx = hi ? min((int)(aq * 0.0625f), 15)                       \
                         : (((int)(aq * 0.5f)) & 15);                         \
            float sq = (float)(idx * idx);                                    \
            ex2 += hi ? sq * 256.f : sq * 16.f;                               \
        }                                                                     \
        lds_pk[wloc][lane + 64 * (EIDX)] = p;                                 \
    }

// per-float4 |y| contribution from LDS-packed int8
#define YPROC(G, B, P)                                                        \
    {                                                                         \
        const float* pg = (const float*)&(G);                                 \
        const float* pb = (const float*)&(B);                                 \
        _Pragma("unroll")                                                     \
        for (int j = 0; j < 4; ++j) {                                         \
            int ii = ((P) << (24 - 8 * j)) >> 24;                             \
            float q = (float)ii * scale_in;                                   \
            float y = (q - mu) * inv * pg[j] + pb[j];                         \
            ym = fmaxf(ym, fabsf(y));                                         \
        }                                                                     \
    }

// per-float4 finalize: requantize from x, scale, NT store
#define OPROC(XV, G, B, EIDX)                                                 \
    {                                                                         \
        const float* px = (const float*)&(XV);                                \
        const float* pg = (const float*)&(G);                                 \
        const float* pb = (const float*)&(B);                                 \
        v4f o;                                                                \
        _Pragma("unroll")                                                     \
        for (int j = 0; j < 4; ++j) {                                         \
            float xi = fminf(fmaxf(rintf(px[j] * r_in), -127.f), 127.f);      \
            float q = xi * scale_in;                                          \
            float y = (q - mu) * inv * pg[j] + pb[j];                         \
            float yi = fminf(fmaxf(rintf(y * r_out), -127.f), 127.f);         \
            o[j] = yi * scale_out;                                            \
        }                                                                     \
        __builtin_nontemporal_store(o, (v4f*)(outr + (lane + 64 * (EIDX)) * 4)); \
    }

// ---- k2: per-row stats + |y|max. 1 row/wave; single x read; pk in LDS.
// No occupancy attributes: the default allocator has produced 64-VGPR
// spill-free code for these exact loop shapes (round 5); pinning it has
// backfired 3/3 times.
__global__ __launch_bounds__(NTHR) void k_rowstats_s(
    const float* __restrict__ x,
    const float* __restrict__ gamma,
    const float* __restrict__ beta,
    const float* __restrict__ blockmax,   // [ABLK] from k1
    float2* __restrict__ row_stats,       // [ROWS] plain stores
    float* __restrict__ bmax2)            // [RBLK] plain stores
{
    const int tid  = threadIdx.x;
    const int lane = tid & 63;
    const int wloc = tid >> 6;
    const int row  = blockIdx.x * WPB + wloc;
    __shared__ float s4[4];
    __shared__ int lds_pk[WPB][NC / 4];   // 16 KB packed int8

    // scale_in: identical deterministic reduce in every block (2/thread)
    float pm = fmaxf(blockmax[tid], blockmax[tid + NTHR]);
    const float gmax = blockMax(pm, s4, tid);
    const float scale_in = gmax * (1.0f / 127.0f);
    const float r_in = 1.0f / scale_in;

    const float4* xr = (const float4*)(x + (size_t)row * NC);
    const float4* g4 = (const float4*)gamma;
    const float4* b4 = (const float4*)beta;

    // pass 1: quantize row -> LDS pk, accumulate Ex/Ex2 (8-deep batches)
    float ex = 0.f, ex2 = 0.f;
    #pragma unroll 1
    for (int e0 = 0; e0 < 16; e0 += 8) {
        float4 v0 = xr[lane + 64 * (e0 + 0)];
        float4 v1 = xr[lane + 64 * (e0 + 1)];
        float4 v2 = xr[lane + 64 * (e0 + 2)];
        float4 v3 = xr[lane + 64 * (e0 + 3)];
        float4 v4 = xr[lane + 64 * (e0 + 4)];
        float4 v5 = xr[lane + 64 * (e0 + 5)];
        float4 v6 = xr[lane + 64 * (e0 + 6)];
        float4 v7 = xr[lane + 64 * (e0 + 7)];
        QPROC(v0, e0 + 0) QPROC(v1, e0 + 1) QPROC(v2, e0 + 2)
        QPROC(v3, e0 + 3) QPROC(v4, e0 + 4) QPROC(v5, e0 + 5)
        QPROC(v6, e0 + 6) QPROC(v7, e0 + 7)
    }
    #pragma unroll
    for (int off = 1; off < 64; off <<= 1) {
        ex  += __shfl_xor(ex,  off, 64);
        ex2 += __shfl_xor(ex2, off, 64);
    }
    ex  = __shfl(ex,  0, 64);
    ex2 = __shfl(ex2, 0, 64);
    float mu, inv;
    rowStatCompute(ex, ex2, &mu, &inv);
    if (lane == 0) row_stats[row] = make_float2(mu, inv);

    // pass 2: row |y| max from LDS pk (same-wave LDS: no barrier needed)
    float ym = 0.f;
    #pragma unroll 1
    for (int e = 0; e < 16; e += 2) {
        float4 gA = g4[lane + 64 * e];
        float4 gB = g4[lane + 64 * (e + 1)];
        float4 bA = b4[lane + 64 * e];
        float4 bB = b4[lane + 64 * (e + 1)];
        int pA = lds_pk[wloc][lane + 64 * e];
        int pB = lds_pk[wloc][lane + 64 * (e + 1)];
        YPROC(gA, bA, pA)
        YPROC(gB, bB, pB)
    }
    #pragma unroll
    for (int off = 1; off < 64; off <<= 1)
        ym = fmaxf(ym, __shfl_xor(ym, off, 64));
    float bym = blockMax(ym, s4, tid);
    if (tid == 0) bmax2[blockIdx.x] = bym;
}

// ---- k3: scale_out reduce + finalize. Requantizes from x (L3-hot) —
// no xi8 round-trip. NT stores.
__global__ __launch_bounds__(NTHR) void k_finalize_s(
    const float* __restrict__ x,
    const float* __restrict__ gamma,
    const float* __restrict__ beta,
    const float* __restrict__ blockmax,   // [ABLK]
    const float* __restrict__ bmax2,      // [RBLK]
    const float2* __restrict__ row_stats, // [ROWS]
    float* __restrict__ out)
{
    const int tid  = threadIdx.x;
    const int lane = tid & 63;
    const int wloc = tid >> 6;
    const int row  = blockIdx.x * WPB + wloc;
    __shared__ float s4[4];

    // scale_in (identical reduce as k2 -> bit-identical)
    float pm = fmaxf(blockmax[tid], blockmax[tid + NTHR]);
    const float gmax = blockMax(pm, s4, tid);
    const float scale_in = gmax * (1.0f / 127.0f);
    const float r_in = 1.0f / scale_in;

    // scale_out: identical deterministic reduce in every block (8/thread)
    float pm2 = 0.f;
    #pragma unroll
    for (int i = 0; i < RBLK / NTHR; ++i)
        pm2 = fmaxf(pm2, bmax2[tid + NTHR * i]);
    const float ygmax = blockMax(pm2, s4, tid);
    const float scale_out = ygmax * (1.f / 127.f);
    const float r_out = 1.f / scale_out;

    const float2 st = row_stats[row];
    const float mu = st.x, inv = st.y;

    const float4* xr = (const float4*)(x + (size_t)row * NC);
    const float4* g4 = (const float4*)gamma;
    const float4* b4 = (const float4*)beta;
    float* outr = out + (size_t)row * NC;

    #pragma unroll 1
    for (int e = 0; e < 16; e += 2) {
        float4 xA = xr[lane + 64 * e];
        float4 xB = xr[lane + 64 * (e + 1)];
        float4 gA = g4[lane + 64 * e];
        float4 gB = g4[lane + 64 * (e + 1)];
        float4 bA = b4[lane + 64 * e];
        float4 bB = b4[lane + 64 * (e + 1)];
        OPROC(xA, gA, bA, e)
        OPROC(xB, gB, bB, e + 1)
    }
}

// ---------------- fallback path (round-2 proven, one row/block) ----------------
__global__ __launch_bounds__(NTHR) void k_absmax(const float* __restrict__ x,
                                                 unsigned int* __restrict__ amax_bits,
                                                 int n4) {
    const float4* x4 = (const float4*)x;
    int t = blockIdx.x * NTHR + threadIdx.x;
    int S = gridDim.x * NTHR;
    float m = 0.f;
    int full = (n4 / (S * 8)) * (S * 8);
    for (int base = t; base < full; base += S * 8) {
        float4 v[8];
        #pragma unroll
        for (int u = 0; u < 8; ++u) v[u] = x4[base + u * S];
        #pragma unroll
        for (int u = 0; u < 8; ++u)
            m = fmaxf(m, fmaxf(fmaxf(fabsf(v[u].x), fabsf(v[u].y)),
                               fmaxf(fabsf(v[u].z), fabsf(v[u].w))));
    }
    for (int i = full + t; i < n4; i += S) {
        float4 v = x4[i];
        m = fmaxf(m, fmaxf(fmaxf(fabsf(v.x), fabsf(v.y)),
                           fmaxf(fabsf(v.z), fabsf(v.w))));
    }
    __shared__ float s4[4];
    float b = blockMax(m, s4, threadIdx.x);
    if (threadIdx.x == 0) atomicMax(amax_bits, __float_as_uint(b));
}

__global__ __launch_bounds__(256) void k_rowstats_fb(
    const float* __restrict__ x, const float* __restrict__ gamma,
    const float* __restrict__ beta, const unsigned int* __restrict__ amax_x_bits,
    unsigned int* __restrict__ amax_y_bits, float2* __restrict__ row_stats,
    int* __restrict__ xi8)
{
    const int row = blockIdx.x;
    const float scale_in = __uint_as_float(*amax_x_bits) * (1.0f / 127.0f);
    const float r_in = 1.0f / scale_in;
    const float4* xr = (const float4*)(x + (size_t)row * NC);
    const float4* g4 = (const float4*)gamma;
    const float4* b4 = (const float4*)beta;
    int pack[4];
    float ex = 0.f, ex2 = 0.f;
    #pragma unroll
    for (int k = 0; k < 4; ++k) {
        float4 v = xr[threadIdx.x + k * 256];
        const float* pv = (const float*)&v;
        int pk = 0;
        #pragma unroll
        for (int j = 0; j < 4; ++j) {
            float xi = fminf(fmaxf(rintf(pv[j] * r_in), -127.f), 127.f);
            int ii = (int)xi;
            pk |= (ii & 255) << (8 * j);
            float q = xi * scale_in;
            ex += q;
            float aq = fabsf(q);
            bool hi = aq >= 64.f;
            int idx = hi ? min((int)(aq * 0.0625f), 15) : (((int)(aq * 0.5f)) & 15);
            float sq = (float)(idx * idx);
            ex2 += hi ? sq * 256.f : sq * 16.f;
        }
        pack[k] = pk;
    }
    int* wr = xi8 + (size_t)row * (NC / 4);
    #pragma unroll
    for (int k = 0; k < 4; ++k) wr[threadIdx.x + k * 256] = pack[k];
    #pragma unroll
    for (int off = 1; off < 64; off <<= 1) {
        ex  += __shfl_xor(ex,  off, 64);
        ex2 += __shfl_xor(ex2, off, 64);
    }
    __shared__ float sred[8];
    __shared__ float sbc[2];
    int lane = threadIdx.x & 63, wid = threadIdx.x >> 6;
    if (lane == 0) { sred[wid] = ex; sred[4 + wid] = ex2; }
    __syncthreads();
    if (threadIdx.x == 0) {
        float Ex  = (sred[0] + sred[1]) + (sred[2] + sred[3]);
        float Ex2 = (sred[4] + sred[5]) + (sred[6] + sred[7]);
        float mu, inv;
        rowStatCompute(Ex, Ex2, &mu, &inv);
        sbc[0] = mu; sbc[1] = inv;
        row_stats[row] = make_float2(mu, inv);
    }
    __syncthreads();
    const float mu = sbc[0], inv = sbc[1];
    float ym = 0.f;
    #pragma unroll
    for (int k = 0; k < 4; ++k) {
        float4 g = g4[threadIdx.x + k * 256];
        float4 b = b4[threadIdx.x + k * 256];
        const float* pg = (const float*)&g;
        const float* pb = (const float*)&b;
        int pk = pack[k];
        #pragma unroll
        for (int j = 0; j < 4; ++j) {
            int ii = (pk << (24 - 8 * j)) >> 24;
            float q = (float)ii * scale_in;
            float y = (q - mu) * inv * pg[j] + pb[j];
            ym = fmaxf(ym, fabsf(y));
        }
    }
    __syncthreads();
    __shared__ float smax[4];
    float b = blockMax(ym, smax, threadIdx.x);
    if (threadIdx.x == 0) atomicMax(amax_y_bits, __float_as_uint(b));
}

__global__ __launch_bounds__(256) void k_finalize_fb(
    const int* __restrict__ xi8, const float* __restrict__ gamma,
    const float* __restrict__ beta, const unsigned int* __restrict__ amax_x_bits,
    const unsigned int* __restrict__ amax_y_bits,
    const float2* __restrict__ row_stats, float* __restrict__ out)
{
    const int row = blockIdx.x;
    const float scale_in  = __uint_as_float(*amax_x_bits) * (1.0f / 127.0f);
    const float scale_out = __uint_as_float(*amax_y_bits) * (1.0f / 127.0f);
    const float r_out = 1.0f / scale_out;
    const float2 st = row_stats[row];
    const float mu = st.x, inv = st.y;
    const int* xr = xi8 + (size_t)row * (NC / 4);
    float4* outr = (float4*)(out + (size_t)row * NC);
    const float4* g4 = (const float4*)gamma;
    const float4* b4 = (const float4*)beta;
    #pragma unroll
    for (int k = 0; k < 4; ++k) {
        int pk = xr[threadIdx.x + k * 256];
        float4 g = g4[threadIdx.x + k * 256];
        float4 b = b4[threadIdx.x + k * 256];
        float4 o;
        const float* pg = (const float*)&g;
        const float* pb = (const float*)&b;
        float* po = (float*)&o;
        #pragma unroll
        for (int j = 0; j < 4; ++j) {
            int ii = (pk << (24 - 8 * j)) >> 24;
            float q = (float)ii * scale_in;
            float y = (q - mu) * inv * pg[j] + pb[j];
            float yi = fminf(fmaxf(rintf(y * r_out), -127.f), 127.f);
            po[j] = yi * scale_out;
        }
        outr[threadIdx.x + k * 256] = o;
    }
}

extern "C" void kernel_launch(void* const* d_in, const int* in_sizes, int n_in,
                              void* d_out, int out_size, void* d_ws, size_t ws_size,
                              hipStream_t stream) {
    const float* x     = (const float*)d_in[0];
    const float* gamma = (const float*)d_in[1];
    const float* beta  = (const float*)d_in[2];
    float* out = (float*)d_out;

    const int n    = in_sizes[0];
    const int rows = n / NC;
    const int n4   = n / 4;

    // split ws layout (all plain-store, no init needed):
    //   blockmax[ABLK] @0, bmax2[RBLK] @2048, row_stats[ROWS] @10240
    const size_t ws_need = 4 * (size_t)ABLK + 4 * (size_t)RBLK + 8 * (size_t)ROWS;

    if (rows == ROWS && n == ROWS * NC && ws_size >= ws_need) {
        float* blockmax   = (float*)d_ws;
        float* bmax2      = (float*)((char*)d_ws + 4 * (size_t)ABLK);
        float2* row_stats = (float2*)((char*)d_ws + 4 * (size_t)ABLK
                                                  + 4 * (size_t)RBLK);
        k_absmax_s<<<ABLK, NTHR, 0, stream>>>(x, blockmax, n4);
        k_rowstats_s<<<RBLK, NTHR, 0, stream>>>(x, gamma, beta, blockmax,
                                                row_stats, bmax2);
        k_finalize_s<<<RBLK, NTHR, 0, stream>>>(x, gamma, beta, blockmax,
                                                bmax2, row_stats, out);
    } else {
        // proven fallback: absmax -> rowstats -> finalize (atomic path)
        unsigned int* amax_x = (unsigned int*)d_ws;
        unsigned int* amax_y = (unsigned int*)((char*)d_ws + 8);
        float2* row_stats    = (float2*)((char*)d_ws + 4096);
        size_t i8_off = (4096 + (size_t)rows * 8 + 255) & ~(size_t)255;
        int* xi8 = (int*)((char*)d_ws + i8_off);

        (void)hipMemsetAsync(d_ws, 0, 4096, stream);
        k_absmax<<<512, NTHR, 0, stream>>>(x, amax_x, n4);
        k_rowstats_fb<<<rows, NTHR, 0, stream>>>(x, gamma, beta, amax_x, amax_y,
                                                 row_stats, xi8);
        k_finalize_fb<<<rows, NTHR, 0, stream>>>(xi8, gamma, beta, amax_x, amax_y,
                                                 row_stats, out);
    }
}